// Round 12
// baseline (469.661 us; speedup 1.0000x reference)
//
#include <hip/hip_runtime.h>
#include <cstddef>

// Problem constants (match reference init_kwargs)
#define N_PTS 9216          // 96^2 grid points
#define KDIM  256           // flattened image dim (1*16*16)
#define PGRID 96
#define NS    9             // int(96*0.1)
// analytic mask: pos = 1/360, neg = -0.5/8855, diag = 0
// torus => every point has exactly 360 neighbors => row-sum(w) = 1 - 0.5 = 0.5

#define BM 128
#define TILES (N_PTS / BM)                 // 72
#define NBLK  (TILES * (TILES + 1) / 2)    // 2628 lower-triangle tiles
#define SLOT_STRIDE 32                     // floats; 128 B per block slot

#define GUARD_T 100.0f      // d2 below this => maybe unsaturated (dist<10)
#define SIM_SAT (-1.0027f)  // sim value when softplus fully saturated

typedef __attribute__((ext_vector_type(8))) __bf16         bf16x8; // MFMA A/B (V8y)
typedef __attribute__((ext_vector_type(4))) float          f32x4;
typedef __attribute__((ext_vector_type(4))) unsigned short u16x4;

__device__ __forceinline__ float bf2f(unsigned short b) {
    union { unsigned int u; float f; } v;
    v.u = ((unsigned int)b) << 16;
    return v.f;
}
__device__ __forceinline__ unsigned short f2bf_rne(float f) {
    union { float f; unsigned int u; } w; w.f = f;
    return (unsigned short)((w.u + 0x7FFFu + ((w.u >> 16) & 1u)) >> 16);
}

// ---------------------------------------------------------------------------
// prep: fp32 -> bf16 copy (RNE) + fp32 row sums of squares. (R10, proven)
// ---------------------------------------------------------------------------
__global__ __launch_bounds__(256) void PeriodicGridRegularization_71640054497944_prep(
        const float* __restrict__ x, unsigned short* __restrict__ xb,
        float* __restrict__ sqv) {
    const int lane = threadIdx.x & 63;
    const int row  = (int)((blockIdx.x * blockDim.x + threadIdx.x) >> 6);
    const f32x4 v  = *(const f32x4*)(x + (size_t)row * KDIM + lane * 4);
    float s = 0.0f;
    u16x4 o;
#pragma unroll
    for (int e = 0; e < 4; ++e) { s = fmaf(v[e], v[e], s); o[e] = f2bf_rne(v[e]); }
    *(u16x4*)(xb + (size_t)row * KDIM + lane * 4) = o;
#pragma unroll
    for (int off = 32; off > 0; off >>= 1) s += __shfl_down(s, off, 64);
    if (lane == 0) sqv[row] = s;
}

// ---------------------------------------------------------------------------
// gram: 128x128 lower-triangle Gram tiles via bf16 MFMA with NO LDS and NO
// barriers. xb (4.7 MB) is L2/L3-resident; each lane loads its fragments
// directly from global (16B bf16x8) with a register ping-pong prefetching
// K-step kt+1 during kt's MFMAs. Waves run fully independent — no drain
// points. Guard epilogue (R8, proven); per-wave partial stores (R10).
// Fragment indexing identical to the proven LDS path: row = base + (lane&15),
// k = kt*32 + (lane>>4)*8.
// ---------------------------------------------------------------------------
__global__ __launch_bounds__(256) void PeriodicGridRegularization_71640054497944_gram(
        const unsigned short* __restrict__ xb,   // bf16 bits [9216][256]
        const float* __restrict__ sqv,           // fp32 row norms^2
        float* __restrict__ part_buf) {          // [NBLK * SLOT_STRIDE]
    const int tid  = threadIdx.x;
    const int lane = tid & 63;
    const int wid  = tid >> 6;
    const int wm   = wid >> 1;
    const int wn   = wid & 1;

    // decode linear block id -> (bi, bj), bj <= bi  (proven R6..R11)
    const int bid = (int)blockIdx.x;
    int bi = (int)((sqrtf(8.0f * (float)bid + 1.0f) - 1.0f) * 0.5f);
    if (bi > TILES - 1) bi = TILES - 1;
    while ((bi + 1) * (bi + 2) / 2 <= bid) ++bi;
    while (bi * (bi + 1) / 2 > bid) --bi;
    const int bj = bid - bi * (bi + 1) / 2;
    const int rowA0 = bi * BM;
    const int rowB0 = bj * BM;

    const int lj = lane & 15;
    const int lg = lane >> 4;           // k-subgroup: k = kt*32 + lg*8

    f32x4 c[4][4];
#pragma unroll
    for (int i = 0; i < 4; ++i)
#pragma unroll
        for (int j = 0; j < 4; ++j)
#pragma unroll
            for (int e = 0; e < 4; ++e) c[i][j][e] = 0.0f;

#if defined(__gfx950__) && __has_builtin(__builtin_amdgcn_mfma_f32_16x16x32_bf16)
    // per-lane fragment base pointers (fragment mf adds mf*16 rows; kt adds 32 elems)
    const unsigned short* pa = xb + (size_t)(rowA0 + wm * 64 + lj) * KDIM + lg * 8;
    const unsigned short* pb = xb + (size_t)(rowB0 + wn * 64 + lj) * KDIM + lg * 8;

    bf16x8 af[2][4], bq[2][4];
#pragma unroll
    for (int mf = 0; mf < 4; ++mf) {
        af[0][mf] = *(const bf16x8*)(pa + mf * 16 * KDIM);
        bq[0][mf] = *(const bf16x8*)(pb + mf * 16 * KDIM);
    }
#pragma unroll
    for (int kt = 0; kt < 8; ++kt) {
        const int cur = kt & 1;
        const int nxt = cur ^ 1;
        if (kt < 7) {
#pragma unroll
            for (int mf = 0; mf < 4; ++mf) {
                af[nxt][mf] = *(const bf16x8*)(pa + mf * 16 * KDIM + (kt + 1) * 32);
                bq[nxt][mf] = *(const bf16x8*)(pb + mf * 16 * KDIM + (kt + 1) * 32);
            }
        }
#pragma unroll
        for (int mf = 0; mf < 4; ++mf)
#pragma unroll
            for (int nf = 0; nf < 4; ++nf)
                c[mf][nf] = __builtin_amdgcn_mfma_f32_16x16x32_bf16(af[cur][mf], bq[cur][nf], c[mf][nf], 0, 0, 0);
    }
#else
    // compile-anywhere fallback (never runs on gfx950): scalar dots from global
#pragma unroll
    for (int mf = 0; mf < 4; ++mf)
#pragma unroll
        for (int nf = 0; nf < 4; ++nf)
#pragma unroll
            for (int r = 0; r < 4; ++r) {
                const int ml = rowA0 + wm * 64 + mf * 16 + (lane >> 4) * 4 + r;
                const int nl = rowB0 + wn * 64 + nf * 16 + lj;
                float s = c[mf][nf][r];
                for (int k = 0; k < KDIM; ++k)
                    s = fmaf(bf2f(xb[(size_t)ml * KDIM + k]), bf2f(xb[(size_t)nl * KDIM + k]), s);
                c[mf][nf][r] = s;
            }
#endif

    // ---------------- guard epilogue (R8, proven) ----------------
    // C/D layout (16x16x32): col = lane&15, row = (lane>>4)*4 + reg
    float sqj[4];
#pragma unroll
    for (int nf = 0; nf < 4; ++nf) sqj[nf] = sqv[rowB0 + wn * 64 + nf * 16 + lj];

    const bool dt = (bi == bj);
    const int  li = (lane >> 4) * 4;

    float mind2 = 1e30f;
#pragma unroll
    for (int mf = 0; mf < 4; ++mf) {
#pragma unroll
        for (int r = 0; r < 4; ++r) {
            const int gi = rowA0 + wm * 64 + mf * 16 + li + r;
            const float si = sqv[gi];
#pragma unroll
            for (int nf = 0; nf < 4; ++nf) {
                const float d2 = fmaf(-2.0f, c[mf][nf][r], si + sqj[nf]);
                const int gj = rowB0 + wn * 64 + nf * 16 + lj;
                const float d2t = (dt && gi == gj) ? 1e30f : d2;
                mind2 = fminf(mind2, d2t);
            }
        }
    }

    float part = 0.0f;
    if (__any(mind2 < GUARD_T)) {
        // exact-correction path (never taken for this data; exact for any data)
        const float WPOS = 1.0f / 360.0f;
        const float WNEG = -0.5f / 8855.0f;
#pragma unroll
        for (int mf = 0; mf < 4; ++mf) {
#pragma unroll
            for (int r = 0; r < 4; ++r) {
                const int gi = rowA0 + wm * 64 + mf * 16 + li + r;
                const float si = sqv[gi];
                const int i0 = gi / PGRID;
                const int i1 = gi - i0 * PGRID;
#pragma unroll
                for (int nf = 0; nf < 4; ++nf) {
                    const int gj = rowB0 + wn * 64 + nf * 16 + lj;
                    const float d2 = fmaf(-2.0f, c[mf][nf][r], si + sqj[nf]);
                    if (!(dt && gi == gj) && d2 < GUARD_T) {
                        const float dist = sqrtf(fmaxf(d2, 0.0f));
                        const float z    = fmaf(-5.0f, dist, 5.0f);
                        const float e    = __expf(-fabsf(z));
                        const float sp   = fmaxf(z, 0.0f) + __logf(1.0f + e);
                        const int j0 = gj / PGRID;
                        const int j1 = gj - j0 * PGRID;
                        int dr = i0 - j0; dr = dr < 0 ? -dr : dr; { const int t = PGRID - dr; dr = dr < t ? dr : t; }
                        int dc = i1 - j1; dc = dc < 0 ? -dc : dc; { const int t = PGRID - dc; dc = dc < t ? dc : t; }
                        const float w = (dr <= NS && dc <= NS) ? WPOS : WNEG;
                        part = fmaf(w * 0.4f, sp, part);   // w*(sim - SIM_SAT)
                    }
                }
            }
        }
    }
    if (bi != bj) part *= 2.0f;   // symmetric counterpart tile

#pragma unroll
    for (int off = 32; off > 0; off >>= 1) part += __shfl_down(part, off, 64);
    if (lane == 0) part_buf[(size_t)bid * SLOT_STRIDE + wid] = part;  // per-wave slot
}

// ---------------------------------------------------------------------------
// fin: sum NBLK per-block f32x4 wave partials, add analytic saturated base,
// dual-format bf16 write (proven). 1 block x 256 threads.
// ---------------------------------------------------------------------------
__global__ __launch_bounds__(256) void PeriodicGridRegularization_71640054497944_fin(
        const float* __restrict__ part_buf, unsigned int* __restrict__ out) {
    __shared__ float red[4];
    const int tid = threadIdx.x;
    float s = 0.0f;
    for (int j = tid; j < NBLK; j += 256) {
        const f32x4 v = *(const f32x4*)(part_buf + (size_t)j * SLOT_STRIDE);
        s += (v[0] + v[1]) + (v[2] + v[3]);
    }
#pragma unroll
    for (int off = 32; off > 0; off >>= 1) s += __shfl_down(s, off, 64);
    if ((tid & 63) == 0) red[tid >> 6] = s;
    __syncthreads();
    if (tid == 0) {
        union { float f; unsigned int u; } w;
        w.f = (red[0] + red[1] + red[2] + red[3]) * (1.0f / (float)N_PTS) + SIM_SAT * 0.5f;
        const unsigned int b = (w.u + 0x7FFFu + ((w.u >> 16) & 1u)) >> 16;
        out[0] = (b << 16) | b;
    }
}

// ---------------------------------------------------------------------------
// Fallback VALU pipeline (round-6 kernel, proven) — used only if ws too small.
// ---------------------------------------------------------------------------
__global__ void PeriodicGridRegularization_71640054497944_init(float* __restrict__ acc) {
    if (threadIdx.x == 0 && blockIdx.x == 0) acc[0] = 0.0f;
}

__global__ __launch_bounds__(256) void PeriodicGridRegularization_71640054497944_valu(
        const float* __restrict__ x, float* __restrict__ acc) {
    __shared__ float As[32][BM + 1];
    __shared__ float Bs[32][BM + 1];
    __shared__ float red[4];
    const int tid = threadIdx.x;
    const int tx  = tid & 15;
    const int ty  = tid >> 4;
    const int bid = (int)blockIdx.x;
    int bi = (int)((sqrtf(8.0f * (float)bid + 1.0f) - 1.0f) * 0.5f);
    if (bi > TILES - 1) bi = TILES - 1;
    while ((bi + 1) * (bi + 2) / 2 <= bid) ++bi;
    while (bi * (bi + 1) / 2 > bid) --bi;
    const int bj = bid - bi * (bi + 1) / 2;
    const int rowA0 = bi * BM, rowB0 = bj * BM;
    float dacc[8][8];
#pragma unroll
    for (int i = 0; i < 8; ++i)
#pragma unroll
        for (int j = 0; j < 8; ++j) dacc[i][j] = 0.0f;
    const int sr = tid >> 1, shalf = tid & 1;
    for (int kt = 0; kt < 8; ++kt) {
        f32x4 va[4], vb[4];
        const float* pa = x + (size_t)(rowA0 + sr) * KDIM + kt * 32 + shalf * 16;
        const float* pb = x + (size_t)(rowB0 + sr) * KDIM + kt * 32 + shalf * 16;
#pragma unroll
        for (int q = 0; q < 4; ++q) { va[q] = *(const f32x4*)(pa + q * 4); vb[q] = *(const f32x4*)(pb + q * 4); }
        __syncthreads();
#pragma unroll
        for (int q = 0; q < 4; ++q)
#pragma unroll
            for (int e = 0; e < 4; ++e) {
                const int k = shalf * 16 + q * 4 + e;
                As[k][sr] = va[q][e];
                Bs[k][sr] = vb[q][e];
            }
        __syncthreads();
#pragma unroll
        for (int k = 0; k < 32; ++k) {
            float a[8], b[8];
#pragma unroll
            for (int i = 0; i < 8; ++i) a[i] = As[k][ty * 8 + i];
#pragma unroll
            for (int j = 0; j < 8; ++j) b[j] = Bs[k][tx * 8 + j];
#pragma unroll
            for (int i = 0; i < 8; ++i)
#pragma unroll
                for (int j = 0; j < 8; ++j) { const float d = a[i] - b[j]; dacc[i][j] = fmaf(d, d, dacc[i][j]); }
        }
    }
    const float WPOS = 1.0f / 360.0f, WNEG = -0.5f / 8855.0f;
    float part = 0.0f;
#pragma unroll
    for (int i = 0; i < 8; ++i) {
        const int gi = rowA0 + ty * 8 + i;
        const int i0 = gi / PGRID, i1 = gi - i0 * PGRID;
#pragma unroll
        for (int j = 0; j < 8; ++j) {
            const int gj = rowB0 + tx * 8 + j;
            const int j0 = gj / PGRID, j1 = gj - j0 * PGRID;
            const float d2 = fmaxf(dacc[i][j], 0.0f);
            const float dist = sqrtf(d2);
            const float z = fmaf(-5.0f, dist, 5.0f);
            const float e = __expf(-fabsf(z));
            const float sp = fmaxf(z, 0.0f) + __logf(1.0f + e);
            const float sim = fmaf(0.4f, sp, -1.0027f);
            int dr = i0 - j0; dr = dr < 0 ? -dr : dr; { const int t = PGRID - dr; dr = dr < t ? dr : t; }
            int dc = i1 - j1; dc = dc < 0 ? -dc : dc; { const int t = PGRID - dc; dc = dc < t ? dc : t; }
            const float w = (gi == gj) ? 0.0f : ((dr <= NS && dc <= NS) ? WPOS : WNEG);
            part = fmaf(w, sim, part);
        }
    }
    if (bi != bj) part *= 2.0f;
#pragma unroll
    for (int off = 32; off > 0; off >>= 1) part += __shfl_down(part, off, 64);
    if ((tid & 63) == 0) red[tid >> 6] = part;
    __syncthreads();
    if (tid == 0) atomicAdd(acc, red[0] + red[1] + red[2] + red[3]);
}

__global__ void PeriodicGridRegularization_71640054497944_finfull(const float* __restrict__ acc,
                                                                  unsigned int* __restrict__ out) {
    if (threadIdx.x == 0 && blockIdx.x == 0) {
        union { float f; unsigned int u; } w;
        w.f = acc[0] * (1.0f / (float)N_PTS);
        const unsigned int b = (w.u + 0x7FFFu + ((w.u >> 16) & 1u)) >> 16;
        out[0] = (b << 16) | b;
    }
}

extern "C" void kernel_launch(void* const* d_in, const int* in_sizes, int n_in,
                              void* d_out, int out_size, void* d_ws, size_t ws_size,
                              hipStream_t stream) {
    const float* x = (const float*)d_in[0];   // images, float32 [9216,256]
    // d_in[1] (neighbor_mask) is analytic -> recomputed in-register, never read.
    const size_t xb_bytes  = (size_t)N_PTS * KDIM * 2;                 // 4.72 MB bf16 copy
    const size_t sqv_bytes = (size_t)N_PTS * 4;
    const size_t pb_bytes  = (size_t)NBLK * SLOT_STRIDE * 4;           // 336 KB partials
    const size_t need      = xb_bytes + sqv_bytes + pb_bytes + 64;

    if (ws_size >= need) {
        unsigned short* xb  = (unsigned short*)d_ws;
        float*          sqv = (float*)((char*)d_ws + xb_bytes);
        float*          pb  = (float*)((char*)d_ws + xb_bytes + sqv_bytes);
        PeriodicGridRegularization_71640054497944_prep<<<N_PTS / 4, 256, 0, stream>>>(x, xb, sqv);
        PeriodicGridRegularization_71640054497944_gram<<<NBLK, 256, 0, stream>>>(xb, sqv, pb);
        PeriodicGridRegularization_71640054497944_fin<<<1, 256, 0, stream>>>(pb, (unsigned int*)d_out);
    } else {
        float* acc = (float*)d_ws;
        PeriodicGridRegularization_71640054497944_init<<<1, 64, 0, stream>>>(acc);
        PeriodicGridRegularization_71640054497944_valu<<<NBLK, 256, 0, stream>>>(x, acc);
        PeriodicGridRegularization_71640054497944_finfull<<<1, 64, 0, stream>>>(acc, (unsigned int*)d_out);
    }
}

// Round 13
// 423.269 us; speedup vs baseline: 1.1096x; 1.1096x over previous
//
#include <hip/hip_runtime.h>
#include <cstddef>

// Problem constants (match reference init_kwargs)
#define N_PTS 9216          // 96^2 grid points
#define KDIM  256           // flattened image dim (1*16*16)
#define PGRID 96
#define NS    9             // int(96*0.1)
// analytic mask: pos = 1/360, neg = -0.5/8855, diag = 0
// torus => every point has exactly 360 neighbors => row-sum(w) = 1 - 0.5 = 0.5

#define BM 128
#define BK 64
#define NKT (KDIM / BK)                    // 4
#define TILES (N_PTS / BM)                 // 72
#define NBLK  (TILES * (TILES + 1) / 2)    // 2628 lower-triangle tiles
#define SLOT_STRIDE 32                     // floats; 128 B per block slot

#define GUARD_T 100.0f      // d2 below this => maybe unsaturated (dist<10)
#define SIM_SAT (-1.0027f)  // sim value when softplus fully saturated
#define KEY_BASE 0x7FFFFFFF // keyed atomicMax encoding for float-min

typedef __attribute__((ext_vector_type(8))) __bf16         bf16x8; // MFMA A/B (V8y)
typedef __attribute__((ext_vector_type(4))) float          f32x4;
typedef __attribute__((ext_vector_type(4))) unsigned int   u32x4;
typedef __attribute__((ext_vector_type(4))) unsigned short u16x4;

__device__ __forceinline__ float bf2f(unsigned short b) {
    union { unsigned int u; float f; } v;
    v.u = ((unsigned int)b) << 16;
    return v.f;
}
__device__ __forceinline__ unsigned short f2bf_rne(float f) {
    union { float f; unsigned int u; } w; w.f = f;
    return (unsigned short)((w.u + 0x7FFFu + ((w.u >> 16) & 1u)) >> 16);
}

// ---------------------------------------------------------------------------
// prep: fp32 -> bf16 copy (RNE) + fp32 row sums of squares + global min of
// sqv via keyed atomicMax (key = KEY_BASE - float_bits; floats are >= 0 so
// int compare is monotone; 0xAAAAAAAA poison is a negative key and loses to
// any real key -> no init kernel needed).
// ---------------------------------------------------------------------------
__global__ __launch_bounds__(256) void PeriodicGridRegularization_71640054497944_prep(
        const float* __restrict__ x, unsigned short* __restrict__ xb,
        float* __restrict__ sqv, int* __restrict__ minkey) {
    const int lane = threadIdx.x & 63;
    const int row  = (int)((blockIdx.x * blockDim.x + threadIdx.x) >> 6);
    const f32x4 v  = *(const f32x4*)(x + (size_t)row * KDIM + lane * 4);
    float s = 0.0f;
    u16x4 o;
#pragma unroll
    for (int e = 0; e < 4; ++e) { s = fmaf(v[e], v[e], s); o[e] = f2bf_rne(v[e]); }
    *(u16x4*)(xb + (size_t)row * KDIM + lane * 4) = o;
#pragma unroll
    for (int off = 32; off > 0; off >>= 1) s += __shfl_down(s, off, 64);
    if (lane == 0) sqv[row] = s;
    // block-level min of the 4 row sums -> one atomic per block
    __shared__ float rs[4];
    if (lane == 0) rs[threadIdx.x >> 6] = s;
    __syncthreads();
    if (threadIdx.x == 0) {
        const float m = fminf(fminf(rs[0], rs[1]), fminf(rs[2], rs[3]));
        union { float f; int i; } u; u.f = m;
        atomicMax(minkey, KEY_BASE - u.i);
    }
}

// ---------------------------------------------------------------------------
// gram: 128x128 lower-triangle Gram tiles via bf16 MFMA (R9/R10 staging:
// BK=64, global_load_lds, XOR chunk swizzle, per-wave partial stores).
// NEW fast-path epilogue: d2 < T  <=>  2c > sqi+sqj-T >= 2*smin-T, so the
// guard needs only cmax (63-op max tree; diagonal tiles mask self-pairs)
// and one wave-uniform compare vs the precomputed global smin — zero loads,
// zero transcendentals in the serial tail. Exact slow path retained.
// ---------------------------------------------------------------------------
__global__ __launch_bounds__(256) void PeriodicGridRegularization_71640054497944_gram(
        const unsigned short* __restrict__ xb,   // bf16 bits [9216][256]
        const float* __restrict__ sqv,           // fp32 row norms^2
        const int* __restrict__ minkey,          // keyed global min of sqv
        float* __restrict__ part_buf) {          // [NBLK * SLOT_STRIDE]
    __shared__ unsigned short As[BM * BK];   // 16 KB
    __shared__ unsigned short Bs[BM * BK];   // 16 KB

    const int tid  = threadIdx.x;
    const int lane = tid & 63;
    const int wid  = tid >> 6;
    const int wm   = wid >> 1;
    const int wn   = wid & 1;

    // decode linear block id -> (bi, bj), bj <= bi  (proven R6..R12)
    const int bid = (int)blockIdx.x;
    int bi = (int)((sqrtf(8.0f * (float)bid + 1.0f) - 1.0f) * 0.5f);
    if (bi > TILES - 1) bi = TILES - 1;
    while ((bi + 1) * (bi + 2) / 2 <= bid) ++bi;
    while (bi * (bi + 1) / 2 > bid) --bi;
    const int bj = bid - bi * (bi + 1) / 2;
    const int rowA0 = bi * BM;
    const int rowB0 = bj * BM;

    f32x4 c[4][4];
#pragma unroll
    for (int i = 0; i < 4; ++i)
#pragma unroll
        for (int j = 0; j < 4; ++j)
#pragma unroll
            for (int e = 0; e < 4; ++e) c[i][j][e] = 0.0f;

    const int lj = lane & 15;
    const int lg = lane >> 4;           // 16-lane group -> k-chunk index base

    for (int kt = 0; kt < NKT; ++kt) {
#if defined(__gfx950__) && __has_builtin(__builtin_amdgcn_global_load_lds) && __has_builtin(__builtin_amdgcn_mfma_f32_16x16x32_bf16)
        __syncthreads();   // previous iteration's LDS reads complete
#pragma unroll
        for (int t = 0; t < 4; ++t) {
            const int s  = t * 256 + tid;       // LDS chunk id 0..1023
            const int r  = s >> 3;              // tile row
            const int p  = s & 7;               // LDS chunk position in row
            const int ch = p ^ (r & 7);         // swizzled global chunk
            const unsigned short* ga = xb + (size_t)(rowA0 + r) * KDIM + kt * BK + ch * 8;
            const unsigned short* gb = xb + (size_t)(rowB0 + r) * KDIM + kt * BK + ch * 8;
            __builtin_amdgcn_global_load_lds(
                (const __attribute__((address_space(1))) void*)ga,
                (__attribute__((address_space(3))) void*)(As + s * 8), 16, 0, 0);
            __builtin_amdgcn_global_load_lds(
                (const __attribute__((address_space(1))) void*)gb,
                (__attribute__((address_space(3))) void*)(Bs + s * 8), 16, 0, 0);
        }
        __syncthreads();   // staging visible

#pragma unroll
        for (int ks = 0; ks < 2; ++ks) {        // two 32-wide K sub-blocks
            bf16x8 a[4], b[4];
#pragma unroll
            for (int mf = 0; mf < 4; ++mf) {
                const int r = wm * 64 + mf * 16 + lj;
                const int p = (ks * 4 + lg) ^ (r & 7);
                a[mf] = *(const bf16x8*)(As + r * BK + p * 8);
            }
#pragma unroll
            for (int nf = 0; nf < 4; ++nf) {
                const int r = wn * 64 + nf * 16 + lj;
                const int p = (ks * 4 + lg) ^ (r & 7);
                b[nf] = *(const bf16x8*)(Bs + r * BK + p * 8);
            }
#pragma unroll
            for (int mf = 0; mf < 4; ++mf)
#pragma unroll
                for (int nf = 0; nf < 4; ++nf)
                    c[mf][nf] = __builtin_amdgcn_mfma_f32_16x16x32_bf16(a[mf], b[nf], c[mf][nf], 0, 0, 0);
        }
#else
        // compile-anywhere fallback (never runs on gfx950)
        u32x4 va[4], vb[4];
#pragma unroll
        for (int t = 0; t < 4; ++t) {
            const int s  = t * 256 + tid;
            const int r  = s >> 3;
            const int p  = s & 7;
            const int ch = p ^ (r & 7);
            va[t] = *(const u32x4*)(xb + (size_t)(rowA0 + r) * KDIM + kt * BK + ch * 8);
            vb[t] = *(const u32x4*)(xb + (size_t)(rowB0 + r) * KDIM + kt * BK + ch * 8);
        }
        __syncthreads();
#pragma unroll
        for (int t = 0; t < 4; ++t) {
            const int s = t * 256 + tid;
            *(u32x4*)(As + s * 8) = va[t];
            *(u32x4*)(Bs + s * 8) = vb[t];
        }
        __syncthreads();
#pragma unroll
        for (int mf = 0; mf < 4; ++mf)
#pragma unroll
            for (int nf = 0; nf < 4; ++nf)
#pragma unroll
                for (int r = 0; r < 4; ++r) {
                    const int ml = wm * 64 + mf * 16 + (lane >> 4) * 4 + r;
                    const int nl = wn * 64 + nf * 16 + lj;
                    float s = c[mf][nf][r];
                    for (int k = 0; k < BK; ++k) {
                        const int pa = (k >> 3) ^ (ml & 7);
                        const int pb = (k >> 3) ^ (nl & 7);
                        s = fmaf(bf2f(As[ml * BK + pa * 8 + (k & 7)]),
                                 bf2f(Bs[nl * BK + pb * 8 + (k & 7)]), s);
                    }
                    c[mf][nf][r] = s;
                }
#endif
    }

    // ---------------- fast guard epilogue ----------------
    // C/D layout (16x16x32): col = lane&15, row = (lane>>4)*4 + reg
    const bool dt = (bi == bj);
    const int  li = (lane >> 4) * 4;

    float cmax = -1e30f;
    if (dt) {
        // diagonal tile: exclude self-pairs from the max
#pragma unroll
        for (int mf = 0; mf < 4; ++mf)
#pragma unroll
            for (int r = 0; r < 4; ++r) {
                const int gi = rowA0 + wm * 64 + mf * 16 + li + r;
#pragma unroll
                for (int nf = 0; nf < 4; ++nf) {
                    const int gj = rowB0 + wn * 64 + nf * 16 + lj;
                    const float cv = (gi == gj) ? -1e30f : c[mf][nf][r];
                    cmax = fmaxf(cmax, cv);
                }
            }
    } else {
#pragma unroll
        for (int mf = 0; mf < 4; ++mf)
#pragma unroll
            for (int nf = 0; nf < 4; ++nf) {
                const f32x4 v = c[mf][nf];
                cmax = fmaxf(cmax, fmaxf(fmaxf(v[0], v[1]), fmaxf(v[2], v[3])));
            }
    }

    // wave-uniform guard: any d2 < T requires 2c > 2*smin - T
    union { float f; int i; } mk; mk.i = KEY_BASE - minkey[0];
    const float smin = mk.f;
    const bool  slow = __any(2.0f * cmax > 2.0f * smin - GUARD_T);

    float part = 0.0f;
    if (slow) {
        // exact-correction path (never taken for this data; exact for any data)
        const float WPOS = 1.0f / 360.0f;
        const float WNEG = -0.5f / 8855.0f;
        float sqj[4];
#pragma unroll
        for (int nf = 0; nf < 4; ++nf) sqj[nf] = sqv[rowB0 + wn * 64 + nf * 16 + lj];
#pragma unroll
        for (int mf = 0; mf < 4; ++mf) {
#pragma unroll
            for (int r = 0; r < 4; ++r) {
                const int gi = rowA0 + wm * 64 + mf * 16 + li + r;
                const float si = sqv[gi];
                const int i0 = gi / PGRID;
                const int i1 = gi - i0 * PGRID;
#pragma unroll
                for (int nf = 0; nf < 4; ++nf) {
                    const int gj = rowB0 + wn * 64 + nf * 16 + lj;
                    const float d2 = fmaf(-2.0f, c[mf][nf][r], si + sqj[nf]);
                    if (!(dt && gi == gj) && d2 < GUARD_T) {
                        const float dist = sqrtf(fmaxf(d2, 0.0f));
                        const float z    = fmaf(-5.0f, dist, 5.0f);
                        const float e    = __expf(-fabsf(z));
                        const float sp   = fmaxf(z, 0.0f) + __logf(1.0f + e);
                        const int j0 = gj / PGRID;
                        const int j1 = gj - j0 * PGRID;
                        int dr = i0 - j0; dr = dr < 0 ? -dr : dr; { const int t = PGRID - dr; dr = dr < t ? dr : t; }
                        int dc = i1 - j1; dc = dc < 0 ? -dc : dc; { const int t = PGRID - dc; dc = dc < t ? dc : t; }
                        const float w = (dr <= NS && dc <= NS) ? WPOS : WNEG;
                        part = fmaf(w * 0.4f, sp, part);   // w*(sim - SIM_SAT)
                    }
                }
            }
        }
        if (bi != bj) part *= 2.0f;   // symmetric counterpart tile
#pragma unroll
        for (int off = 32; off > 0; off >>= 1) part += __shfl_down(part, off, 64);
    }
    if (lane == 0) part_buf[(size_t)bid * SLOT_STRIDE + wid] = part;  // per-wave slot
}

// ---------------------------------------------------------------------------
// fin: sum NBLK per-block f32x4 wave partials, add analytic saturated base,
// dual-format bf16 write (proven). 1 block x 256 threads.
// ---------------------------------------------------------------------------
__global__ __launch_bounds__(256) void PeriodicGridRegularization_71640054497944_fin(
        const float* __restrict__ part_buf, unsigned int* __restrict__ out) {
    __shared__ float red[4];
    const int tid = threadIdx.x;
    float s = 0.0f;
    for (int j = tid; j < NBLK; j += 256) {
        const f32x4 v = *(const f32x4*)(part_buf + (size_t)j * SLOT_STRIDE);
        s += (v[0] + v[1]) + (v[2] + v[3]);
    }
#pragma unroll
    for (int off = 32; off > 0; off >>= 1) s += __shfl_down(s, off, 64);
    if ((tid & 63) == 0) red[tid >> 6] = s;
    __syncthreads();
    if (tid == 0) {
        union { float f; unsigned int u; } w;
        w.f = (red[0] + red[1] + red[2] + red[3]) * (1.0f / (float)N_PTS) + SIM_SAT * 0.5f;
        const unsigned int b = (w.u + 0x7FFFu + ((w.u >> 16) & 1u)) >> 16;
        out[0] = (b << 16) | b;
    }
}

// ---------------------------------------------------------------------------
// Fallback VALU pipeline (round-6 kernel, proven) — used only if ws too small.
// ---------------------------------------------------------------------------
__global__ void PeriodicGridRegularization_71640054497944_init(float* __restrict__ acc) {
    if (threadIdx.x == 0 && blockIdx.x == 0) acc[0] = 0.0f;
}

__global__ __launch_bounds__(256) void PeriodicGridRegularization_71640054497944_valu(
        const float* __restrict__ x, float* __restrict__ acc) {
    __shared__ float As[32][BM + 1];
    __shared__ float Bs[32][BM + 1];
    __shared__ float red[4];
    const int tid = threadIdx.x;
    const int tx  = tid & 15;
    const int ty  = tid >> 4;
    const int bid = (int)blockIdx.x;
    int bi = (int)((sqrtf(8.0f * (float)bid + 1.0f) - 1.0f) * 0.5f);
    if (bi > TILES - 1) bi = TILES - 1;
    while ((bi + 1) * (bi + 2) / 2 <= bid) ++bi;
    while (bi * (bi + 1) / 2 > bid) --bi;
    const int bj = bid - bi * (bi + 1) / 2;
    const int rowA0 = bi * BM, rowB0 = bj * BM;
    float dacc[8][8];
#pragma unroll
    for (int i = 0; i < 8; ++i)
#pragma unroll
        for (int j = 0; j < 8; ++j) dacc[i][j] = 0.0f;
    const int sr = tid >> 1, shalf = tid & 1;
    for (int kt = 0; kt < 8; ++kt) {
        f32x4 va[4], vb[4];
        const float* pa = x + (size_t)(rowA0 + sr) * KDIM + kt * 32 + shalf * 16;
        const float* pb = x + (size_t)(rowB0 + sr) * KDIM + kt * 32 + shalf * 16;
#pragma unroll
        for (int q = 0; q < 4; ++q) { va[q] = *(const f32x4*)(pa + q * 4); vb[q] = *(const f32x4*)(pb + q * 4); }
        __syncthreads();
#pragma unroll
        for (int q = 0; q < 4; ++q)
#pragma unroll
            for (int e = 0; e < 4; ++e) {
                const int k = shalf * 16 + q * 4 + e;
                As[k][sr] = va[q][e];
                Bs[k][sr] = vb[q][e];
            }
        __syncthreads();
#pragma unroll
        for (int k = 0; k < 32; ++k) {
            float a[8], b[8];
#pragma unroll
            for (int i = 0; i < 8; ++i) a[i] = As[k][ty * 8 + i];
#pragma unroll
            for (int j = 0; j < 8; ++j) b[j] = Bs[k][tx * 8 + j];
#pragma unroll
            for (int i = 0; i < 8; ++i)
#pragma unroll
                for (int j = 0; j < 8; ++j) { const float d = a[i] - b[j]; dacc[i][j] = fmaf(d, d, dacc[i][j]); }
        }
    }
    const float WPOS = 1.0f / 360.0f, WNEG = -0.5f / 8855.0f;
    float part = 0.0f;
#pragma unroll
    for (int i = 0; i < 8; ++i) {
        const int gi = rowA0 + ty * 8 + i;
        const int i0 = gi / PGRID, i1 = gi - i0 * PGRID;
#pragma unroll
        for (int j = 0; j < 8; ++j) {
            const int gj = rowB0 + tx * 8 + j;
            const int j0 = gj / PGRID, j1 = gj - j0 * PGRID;
            const float d2 = fmaxf(dacc[i][j], 0.0f);
            const float dist = sqrtf(d2);
            const float z = fmaf(-5.0f, dist, 5.0f);
            const float e = __expf(-fabsf(z));
            const float sp = fmaxf(z, 0.0f) + __logf(1.0f + e);
            const float sim = fmaf(0.4f, sp, -1.0027f);
            int dr = i0 - j0; dr = dr < 0 ? -dr : dr; { const int t = PGRID - dr; dr = dr < t ? dr : t; }
            int dc = i1 - j1; dc = dc < 0 ? -dc : dc; { const int t = PGRID - dc; dc = dc < t ? dc : t; }
            const float w = (gi == gj) ? 0.0f : ((dr <= NS && dc <= NS) ? WPOS : WNEG);
            part = fmaf(w, sim, part);
        }
    }
    if (bi != bj) part *= 2.0f;
#pragma unroll
    for (int off = 32; off > 0; off >>= 1) part += __shfl_down(part, off, 64);
    if ((tid & 63) == 0) red[tid >> 6] = part;
    __syncthreads();
    if (tid == 0) atomicAdd(acc, red[0] + red[1] + red[2] + red[3]);
}

__global__ void PeriodicGridRegularization_71640054497944_finfull(const float* __restrict__ acc,
                                                                  unsigned int* __restrict__ out) {
    if (threadIdx.x == 0 && blockIdx.x == 0) {
        union { float f; unsigned int u; } w;
        w.f = acc[0] * (1.0f / (float)N_PTS);
        const unsigned int b = (w.u + 0x7FFFu + ((w.u >> 16) & 1u)) >> 16;
        out[0] = (b << 16) | b;
    }
}

extern "C" void kernel_launch(void* const* d_in, const int* in_sizes, int n_in,
                              void* d_out, int out_size, void* d_ws, size_t ws_size,
                              hipStream_t stream) {
    const float* x = (const float*)d_in[0];   // images, float32 [9216,256]
    // d_in[1] (neighbor_mask) is analytic -> recomputed in-register, never read.
    const size_t xb_bytes  = (size_t)N_PTS * KDIM * 2;                 // 4.72 MB bf16 copy
    const size_t sqv_bytes = (size_t)N_PTS * 4;
    const size_t pb_bytes  = (size_t)NBLK * SLOT_STRIDE * 4;           // 336 KB partials
    const size_t need      = xb_bytes + sqv_bytes + pb_bytes + 128;

    if (ws_size >= need) {
        unsigned short* xb  = (unsigned short*)d_ws;
        float*          sqv = (float*)((char*)d_ws + xb_bytes);
        float*          pb  = (float*)((char*)d_ws + xb_bytes + sqv_bytes);
        int*            mk  = (int*)((char*)d_ws + xb_bytes + sqv_bytes + pb_bytes);
        PeriodicGridRegularization_71640054497944_prep<<<N_PTS / 4, 256, 0, stream>>>(x, xb, sqv, mk);
        PeriodicGridRegularization_71640054497944_gram<<<NBLK, 256, 0, stream>>>(xb, sqv, mk, pb);
        PeriodicGridRegularization_71640054497944_fin<<<1, 256, 0, stream>>>(pb, (unsigned int*)d_out);
    } else {
        float* acc = (float*)d_ws;
        PeriodicGridRegularization_71640054497944_init<<<1, 64, 0, stream>>>(acc);
        PeriodicGridRegularization_71640054497944_valu<<<NBLK, 256, 0, stream>>>(x, acc);
        PeriodicGridRegularization_71640054497944_finfull<<<1, 64, 0, stream>>>(acc, (unsigned int*)d_out);
    }
}

// Round 14
// 410.085 us; speedup vs baseline: 1.1453x; 1.0321x over previous
//
#include <hip/hip_runtime.h>
#include <cstddef>

// Problem constants (match reference init_kwargs)
#define N_PTS 9216          // 96^2 grid points
#define KDIM  256           // flattened image dim (1*16*16)
#define PGRID 96
#define NS    9             // int(96*0.1)
// analytic mask: pos = 1/360, neg = -0.5/8855, diag = 0
// torus => every point has exactly 360 neighbors => row-sum(w) = 1 - 0.5 = 0.5

#define BM 128
#define BK 64
#define NKT (KDIM / BK)                    // 4
#define TILES (N_PTS / BM)                 // 72
#define NBLK  (TILES * (TILES + 1) / 2)    // 2628 lower-triangle tiles
#define SLOT_STRIDE 32                     // floats; 128 B -> one cache line per slot

#define GUARD_T 100.0f      // d2 below this => softplus not saturated
#define SIM_SAT (-1.0027f)  // sim value when softplus fully saturated

typedef __attribute__((ext_vector_type(8))) __bf16         bf16x8; // MFMA A/B (V8y)
typedef __attribute__((ext_vector_type(4))) float          f32x4;
typedef __attribute__((ext_vector_type(4))) unsigned int   u32x4;
typedef __attribute__((ext_vector_type(4))) unsigned short u16x4;

__device__ __forceinline__ float bf2f(unsigned short b) {
    union { unsigned int u; float f; } v;
    v.u = ((unsigned int)b) << 16;
    return v.f;
}
__device__ __forceinline__ unsigned short f2bf_rne(float f) {
    union { float f; unsigned int u; } w; w.f = f;
    return (unsigned short)((w.u + 0x7FFFu + ((w.u >> 16) & 1u)) >> 16);
}

// ---------------------------------------------------------------------------
// prep: fp32 -> bf16 copy (RNE) + fp32 row sums of squares. (proven R10)
// ---------------------------------------------------------------------------
__global__ __launch_bounds__(256) void PeriodicGridRegularization_71640054497944_prep(
        const float* __restrict__ x, unsigned short* __restrict__ xb,
        float* __restrict__ sqv) {
    const int lane = threadIdx.x & 63;
    const int row  = (int)((blockIdx.x * blockDim.x + threadIdx.x) >> 6);
    const f32x4 v  = *(const f32x4*)(x + (size_t)row * KDIM + lane * 4);
    float s = 0.0f;
    u16x4 o;
#pragma unroll
    for (int e = 0; e < 4; ++e) { s = fmaf(v[e], v[e], s); o[e] = f2bf_rne(v[e]); }
    *(u16x4*)(xb + (size_t)row * KDIM + lane * 4) = o;
#pragma unroll
    for (int off = 32; off > 0; off >>= 1) s += __shfl_down(s, off, 64);
    if (lane == 0) sqv[row] = s;
}

// ---------------------------------------------------------------------------
// gram: 128x128 lower-triangle Gram tiles via bf16 MFMA (BK=64,
// global_load_lds width-16, XOR chunk swizzle on the global side so the LDS
// destination stays lane-linear). Guard epilogue (R8, proven): fast path
// tracks min off-diagonal d2 only; exact correction path for d2 < GUARD_T
// (never taken for this data, exact for any input). Per-block slot stores
// (no atomics). This is the best-measured configuration (R10: 410.4 us).
// ---------------------------------------------------------------------------
__global__ __launch_bounds__(256) void PeriodicGridRegularization_71640054497944_gram(
        const unsigned short* __restrict__ xb,   // bf16 bits [9216][256]
        const float* __restrict__ sqv,           // fp32 row norms^2
        float* __restrict__ part_buf) {          // [NBLK * SLOT_STRIDE]
    __shared__ unsigned short As[BM * BK];   // 16 KB
    __shared__ unsigned short Bs[BM * BK];   // 16 KB
    __shared__ float red[4];

    const int tid  = threadIdx.x;
    const int lane = tid & 63;
    const int wid  = tid >> 6;
    const int wm   = wid >> 1;
    const int wn   = wid & 1;

    // decode linear block id -> (bi, bj), bj <= bi  (proven R6..R13)
    const int bid = (int)blockIdx.x;
    int bi = (int)((sqrtf(8.0f * (float)bid + 1.0f) - 1.0f) * 0.5f);
    if (bi > TILES - 1) bi = TILES - 1;
    while ((bi + 1) * (bi + 2) / 2 <= bid) ++bi;
    while (bi * (bi + 1) / 2 > bid) --bi;
    const int bj = bid - bi * (bi + 1) / 2;
    const int rowA0 = bi * BM;
    const int rowB0 = bj * BM;

    f32x4 c[4][4];
#pragma unroll
    for (int i = 0; i < 4; ++i)
#pragma unroll
        for (int j = 0; j < 4; ++j)
#pragma unroll
            for (int e = 0; e < 4; ++e) c[i][j][e] = 0.0f;

    const int lj = lane & 15;
    const int lg = lane >> 4;           // 16-lane group -> k-chunk index base

    for (int kt = 0; kt < NKT; ++kt) {
#if defined(__gfx950__) && __has_builtin(__builtin_amdgcn_global_load_lds) && __has_builtin(__builtin_amdgcn_mfma_f32_16x16x32_bf16)
        __syncthreads();   // previous iteration's LDS reads complete
#pragma unroll
        for (int t = 0; t < 4; ++t) {
            const int s  = t * 256 + tid;       // LDS chunk id 0..1023
            const int r  = s >> 3;              // tile row
            const int p  = s & 7;               // LDS chunk position in row
            const int ch = p ^ (r & 7);         // swizzled global chunk
            const unsigned short* ga = xb + (size_t)(rowA0 + r) * KDIM + kt * BK + ch * 8;
            const unsigned short* gb = xb + (size_t)(rowB0 + r) * KDIM + kt * BK + ch * 8;
            __builtin_amdgcn_global_load_lds(
                (const __attribute__((address_space(1))) void*)ga,
                (__attribute__((address_space(3))) void*)(As + s * 8), 16, 0, 0);
            __builtin_amdgcn_global_load_lds(
                (const __attribute__((address_space(1))) void*)gb,
                (__attribute__((address_space(3))) void*)(Bs + s * 8), 16, 0, 0);
        }
        __syncthreads();   // staging visible

#pragma unroll
        for (int ks = 0; ks < 2; ++ks) {        // two 32-wide K sub-blocks
            bf16x8 a[4], b[4];
#pragma unroll
            for (int mf = 0; mf < 4; ++mf) {
                const int r = wm * 64 + mf * 16 + lj;
                const int p = (ks * 4 + lg) ^ (r & 7);
                a[mf] = *(const bf16x8*)(As + r * BK + p * 8);
            }
#pragma unroll
            for (int nf = 0; nf < 4; ++nf) {
                const int r = wn * 64 + nf * 16 + lj;
                const int p = (ks * 4 + lg) ^ (r & 7);
                b[nf] = *(const bf16x8*)(Bs + r * BK + p * 8);
            }
#pragma unroll
            for (int mf = 0; mf < 4; ++mf)
#pragma unroll
                for (int nf = 0; nf < 4; ++nf)
                    c[mf][nf] = __builtin_amdgcn_mfma_f32_16x16x32_bf16(a[mf], b[nf], c[mf][nf], 0, 0, 0);
        }
#else
        // compile-anywhere fallback (never runs on gfx950)
        u32x4 va[4], vb[4];
#pragma unroll
        for (int t = 0; t < 4; ++t) {
            const int s  = t * 256 + tid;
            const int r  = s >> 3;
            const int p  = s & 7;
            const int ch = p ^ (r & 7);
            va[t] = *(const u32x4*)(xb + (size_t)(rowA0 + r) * KDIM + kt * BK + ch * 8);
            vb[t] = *(const u32x4*)(xb + (size_t)(rowB0 + r) * KDIM + kt * BK + ch * 8);
        }
        __syncthreads();
#pragma unroll
        for (int t = 0; t < 4; ++t) {
            const int s = t * 256 + tid;
            *(u32x4*)(As + s * 8) = va[t];
            *(u32x4*)(Bs + s * 8) = vb[t];
        }
        __syncthreads();
#pragma unroll
        for (int mf = 0; mf < 4; ++mf)
#pragma unroll
            for (int nf = 0; nf < 4; ++nf)
#pragma unroll
                for (int r = 0; r < 4; ++r) {
                    const int ml = wm * 64 + mf * 16 + (lane >> 4) * 4 + r;
                    const int nl = wn * 64 + nf * 16 + lj;
                    float s = c[mf][nf][r];
                    for (int k = 0; k < BK; ++k) {
                        const int pa = (k >> 3) ^ (ml & 7);
                        const int pb = (k >> 3) ^ (nl & 7);
                        s = fmaf(bf2f(As[ml * BK + pa * 8 + (k & 7)]),
                                 bf2f(Bs[nl * BK + pb * 8 + (k & 7)]), s);
                    }
                    c[mf][nf][r] = s;
                }
#endif
    }

    // ---------------- guard epilogue (R8, proven) ----------------
    // C/D layout (16x16x32): col = lane&15, row = (lane>>4)*4 + reg
    float sqj[4];
#pragma unroll
    for (int nf = 0; nf < 4; ++nf) sqj[nf] = sqv[rowB0 + wn * 64 + nf * 16 + lj];

    const bool dt = (bi == bj);
    const int  li = (lane >> 4) * 4;

    float mind2 = 1e30f;
#pragma unroll
    for (int mf = 0; mf < 4; ++mf) {
#pragma unroll
        for (int r = 0; r < 4; ++r) {
            const int gi = rowA0 + wm * 64 + mf * 16 + li + r;
            const float si = sqv[gi];
#pragma unroll
            for (int nf = 0; nf < 4; ++nf) {
                const float d2 = fmaf(-2.0f, c[mf][nf][r], si + sqj[nf]);
                const int gj = rowB0 + wn * 64 + nf * 16 + lj;
                const float d2t = (dt && gi == gj) ? 1e30f : d2;
                mind2 = fminf(mind2, d2t);
            }
        }
    }

    float part = 0.0f;
    if (__any(mind2 < GUARD_T)) {
        // exact-correction path (never taken for this data; exact for any data)
        const float WPOS = 1.0f / 360.0f;
        const float WNEG = -0.5f / 8855.0f;
#pragma unroll
        for (int mf = 0; mf < 4; ++mf) {
#pragma unroll
            for (int r = 0; r < 4; ++r) {
                const int gi = rowA0 + wm * 64 + mf * 16 + li + r;
                const float si = sqv[gi];
                const int i0 = gi / PGRID;
                const int i1 = gi - i0 * PGRID;
#pragma unroll
                for (int nf = 0; nf < 4; ++nf) {
                    const int gj = rowB0 + wn * 64 + nf * 16 + lj;
                    const float d2 = fmaf(-2.0f, c[mf][nf][r], si + sqj[nf]);
                    if (!(dt && gi == gj) && d2 < GUARD_T) {
                        const float dist = sqrtf(fmaxf(d2, 0.0f));
                        const float z    = fmaf(-5.0f, dist, 5.0f);
                        const float e    = __expf(-fabsf(z));
                        const float sp   = fmaxf(z, 0.0f) + __logf(1.0f + e);
                        const int j0 = gj / PGRID;
                        const int j1 = gj - j0 * PGRID;
                        int dr = i0 - j0; dr = dr < 0 ? -dr : dr; { const int t = PGRID - dr; dr = dr < t ? dr : t; }
                        int dc = i1 - j1; dc = dc < 0 ? -dc : dc; { const int t = PGRID - dc; dc = dc < t ? dc : t; }
                        const float w = (dr <= NS && dc <= NS) ? WPOS : WNEG;
                        part = fmaf(w * 0.4f, sp, part);   // w*(sim - SIM_SAT)
                    }
                }
            }
        }
    }
    if (bi != bj) part *= 2.0f;   // symmetric counterpart tile

#pragma unroll
    for (int off = 32; off > 0; off >>= 1) part += __shfl_down(part, off, 64);
    if (lane == 0) red[wid] = part;
    __syncthreads();
    if (tid == 0) part_buf[(size_t)bid * SLOT_STRIDE] = red[0] + red[1] + red[2] + red[3];
}

// ---------------------------------------------------------------------------
// fin: sum NBLK per-block partials, add analytic saturated base, dual-format
// bf16 write (proven). 1 block x 256 threads.
// ---------------------------------------------------------------------------
__global__ __launch_bounds__(256) void PeriodicGridRegularization_71640054497944_fin(
        const float* __restrict__ part_buf, unsigned int* __restrict__ out) {
    __shared__ float red[4];
    const int tid = threadIdx.x;
    float s = 0.0f;
    for (int j = tid; j < NBLK; j += 256) s += part_buf[(size_t)j * SLOT_STRIDE];
#pragma unroll
    for (int off = 32; off > 0; off >>= 1) s += __shfl_down(s, off, 64);
    if ((tid & 63) == 0) red[tid >> 6] = s;
    __syncthreads();
    if (tid == 0) {
        union { float f; unsigned int u; } w;
        w.f = (red[0] + red[1] + red[2] + red[3]) * (1.0f / (float)N_PTS) + SIM_SAT * 0.5f;
        const unsigned int b = (w.u + 0x7FFFu + ((w.u >> 16) & 1u)) >> 16;
        out[0] = (b << 16) | b;
    }
}

// ---------------------------------------------------------------------------
// Fallback VALU pipeline (round-6 kernel, proven) — used only if ws too small.
// ---------------------------------------------------------------------------
__global__ void PeriodicGridRegularization_71640054497944_init(float* __restrict__ acc) {
    if (threadIdx.x == 0 && blockIdx.x == 0) acc[0] = 0.0f;
}

__global__ __launch_bounds__(256) void PeriodicGridRegularization_71640054497944_valu(
        const float* __restrict__ x, float* __restrict__ acc) {
    __shared__ float As[32][BM + 1];
    __shared__ float Bs[32][BM + 1];
    __shared__ float red[4];
    const int tid = threadIdx.x;
    const int tx  = tid & 15;
    const int ty  = tid >> 4;
    const int bid = (int)blockIdx.x;
    int bi = (int)((sqrtf(8.0f * (float)bid + 1.0f) - 1.0f) * 0.5f);
    if (bi > TILES - 1) bi = TILES - 1;
    while ((bi + 1) * (bi + 2) / 2 <= bid) ++bi;
    while (bi * (bi + 1) / 2 > bid) --bi;
    const int bj = bid - bi * (bi + 1) / 2;
    const int rowA0 = bi * BM, rowB0 = bj * BM;
    float dacc[8][8];
#pragma unroll
    for (int i = 0; i < 8; ++i)
#pragma unroll
        for (int j = 0; j < 8; ++j) dacc[i][j] = 0.0f;
    const int sr = tid >> 1, shalf = tid & 1;
    for (int kt = 0; kt < 8; ++kt) {
        f32x4 va[4], vb[4];
        const float* pa = x + (size_t)(rowA0 + sr) * KDIM + kt * 32 + shalf * 16;
        const float* pb = x + (size_t)(rowB0 + sr) * KDIM + kt * 32 + shalf * 16;
#pragma unroll
        for (int q = 0; q < 4; ++q) { va[q] = *(const f32x4*)(pa + q * 4); vb[q] = *(const f32x4*)(pb + q * 4); }
        __syncthreads();
#pragma unroll
        for (int q = 0; q < 4; ++q)
#pragma unroll
            for (int e = 0; e < 4; ++e) {
                const int k = shalf * 16 + q * 4 + e;
                As[k][sr] = va[q][e];
                Bs[k][sr] = vb[q][e];
            }
        __syncthreads();
#pragma unroll
        for (int k = 0; k < 32; ++k) {
            float a[8], b[8];
#pragma unroll
            for (int i = 0; i < 8; ++i) a[i] = As[k][ty * 8 + i];
#pragma unroll
            for (int j = 0; j < 8; ++j) b[j] = Bs[k][tx * 8 + j];
#pragma unroll
            for (int i = 0; i < 8; ++i)
#pragma unroll
                for (int j = 0; j < 8; ++j) { const float d = a[i] - b[j]; dacc[i][j] = fmaf(d, d, dacc[i][j]); }
        }
    }
    const float WPOS = 1.0f / 360.0f, WNEG = -0.5f / 8855.0f;
    float part = 0.0f;
#pragma unroll
    for (int i = 0; i < 8; ++i) {
        const int gi = rowA0 + ty * 8 + i;
        const int i0 = gi / PGRID, i1 = gi - i0 * PGRID;
#pragma unroll
        for (int j = 0; j < 8; ++j) {
            const int gj = rowB0 + tx * 8 + j;
            const int j0 = gj / PGRID, j1 = gj - j0 * PGRID;
            const float d2 = fmaxf(dacc[i][j], 0.0f);
            const float dist = sqrtf(d2);
            const float z = fmaf(-5.0f, dist, 5.0f);
            const float e = __expf(-fabsf(z));
            const float sp = fmaxf(z, 0.0f) + __logf(1.0f + e);
            const float sim = fmaf(0.4f, sp, -1.0027f);
            int dr = i0 - j0; dr = dr < 0 ? -dr : dr; { const int t = PGRID - dr; dr = dr < t ? dr : t; }
            int dc = i1 - j1; dc = dc < 0 ? -dc : dc; { const int t = PGRID - dc; dc = dc < t ? dc : t; }
            const float w = (gi == gj) ? 0.0f : ((dr <= NS && dc <= NS) ? WPOS : WNEG);
            part = fmaf(w, sim, part);
        }
    }
    if (bi != bj) part *= 2.0f;
#pragma unroll
    for (int off = 32; off > 0; off >>= 1) part += __shfl_down(part, off, 64);
    if ((tid & 63) == 0) red[tid >> 6] = part;
    __syncthreads();
    if (tid == 0) atomicAdd(acc, red[0] + red[1] + red[2] + red[3]);
}

__global__ void PeriodicGridRegularization_71640054497944_finfull(const float* __restrict__ acc,
                                                                  unsigned int* __restrict__ out) {
    if (threadIdx.x == 0 && blockIdx.x == 0) {
        union { float f; unsigned int u; } w;
        w.f = acc[0] * (1.0f / (float)N_PTS);
        const unsigned int b = (w.u + 0x7FFFu + ((w.u >> 16) & 1u)) >> 16;
        out[0] = (b << 16) | b;
    }
}

extern "C" void kernel_launch(void* const* d_in, const int* in_sizes, int n_in,
                              void* d_out, int out_size, void* d_ws, size_t ws_size,
                              hipStream_t stream) {
    const float* x = (const float*)d_in[0];   // images, float32 [9216,256]
    // d_in[1] (neighbor_mask) is analytic -> recomputed in-register, never read.
    const size_t xb_bytes  = (size_t)N_PTS * KDIM * 2;                 // 4.72 MB bf16 copy
    const size_t sqv_bytes = (size_t)N_PTS * 4;
    const size_t pb_bytes  = (size_t)NBLK * SLOT_STRIDE * 4;           // 336 KB partials
    const size_t need      = xb_bytes + sqv_bytes + pb_bytes + 64;

    if (ws_size >= need) {
        unsigned short* xb  = (unsigned short*)d_ws;
        float*          sqv = (float*)((char*)d_ws + xb_bytes);
        float*          pb  = (float*)((char*)d_ws + xb_bytes + sqv_bytes);
        PeriodicGridRegularization_71640054497944_prep<<<N_PTS / 4, 256, 0, stream>>>(x, xb, sqv);
        PeriodicGridRegularization_71640054497944_gram<<<NBLK, 256, 0, stream>>>(xb, sqv, pb);
        PeriodicGridRegularization_71640054497944_fin<<<1, 256, 0, stream>>>(pb, (unsigned int*)d_out);
    } else {
        float* acc = (float*)d_ws;
        PeriodicGridRegularization_71640054497944_init<<<1, 64, 0, stream>>>(acc);
        PeriodicGridRegularization_71640054497944_valu<<<NBLK, 256, 0, stream>>>(x, acc);
        PeriodicGridRegularization_71640054497944_finfull<<<1, 64, 0, stream>>>(acc, (unsigned int*)d_out);
    }
}